// Round 1
// baseline (8477.047 us; speedup 1.0000x reference)
//
#include <hip/hip_runtime.h>
#include <math.h>

#define B_ 16
#define N_ 2048
#define M_ 2048
#define ITERS_ 100
#define SPLIT_ 16
#define CHUNK_ (N_ / SPLIT_)

// (1/eps) * log2(e), eps = 0.1
#define SCALE_ 14.426950408889634f
#define LN2_ 0.69314718055994531f

static __device__ __forceinline__ float wave_red_max(float x) {
#pragma unroll
  for (int o = 32; o; o >>= 1) x = fmaxf(x, __shfl_xor(x, o, 64));
  return x;
}
static __device__ __forceinline__ float wave_red_sum(float x) {
#pragma unroll
  for (int o = 32; o; o >>= 1) x += __shfl_xor(x, o, 64);
  return x;
}

// u[b,n] = eps*(log(p+1e-8) - LSE_m((v[b,m]-C[b,n,m])/eps))
// one block per (b,n) row; 256 threads x 8 elements (2x float4)
__global__ __launch_bounds__(256) void row_kernel(
    const float* __restrict__ C, const float* __restrict__ p,
    const float* __restrict__ v, float* __restrict__ u) {
  int bid = blockIdx.x;  // b*N_ + n
  int tid = threadIdx.x;
  int b = bid >> 11;  // N_ = 2048
  const float4* Cr = (const float4*)(C + (size_t)bid * M_);
  const float4* vr = (const float4*)(v + (size_t)b * M_);
  float4 c0 = Cr[tid], c1 = Cr[tid + 256];
  float4 v0 = vr[tid], v1 = vr[tid + 256];
  float t[8];
  t[0] = (v0.x - c0.x) * SCALE_;
  t[1] = (v0.y - c0.y) * SCALE_;
  t[2] = (v0.z - c0.z) * SCALE_;
  t[3] = (v0.w - c0.w) * SCALE_;
  t[4] = (v1.x - c1.x) * SCALE_;
  t[5] = (v1.y - c1.y) * SCALE_;
  t[6] = (v1.z - c1.z) * SCALE_;
  t[7] = (v1.w - c1.w) * SCALE_;
  float tm = t[0];
#pragma unroll
  for (int j = 1; j < 8; j++) tm = fmaxf(tm, t[j]);

  __shared__ float sred[8];
  int lane = tid & 63, wid = tid >> 6;
  float wm = wave_red_max(tm);
  if (!lane) sred[wid] = wm;
  __syncthreads();
  float bm = fmaxf(fmaxf(sred[0], sred[1]), fmaxf(sred[2], sred[3]));

  float s = 0.f;
#pragma unroll
  for (int j = 0; j < 8; j++) s += exp2f(t[j] - bm);
  float wsum = wave_red_sum(s);
  if (!lane) sred[4 + wid] = wsum;
  __syncthreads();
  if (!tid) {
    float bs = sred[4] + sred[5] + sred[6] + sred[7];
    float lse = LN2_ * (bm + log2f(bs));
    u[bid] = 0.1f * (logf(p[bid] + 1e-8f) - lse);
  }
}

// partial column LSE over an n-chunk: online (max,sum) per column
// grid = B_ * (M_/256) * SPLIT_; 256 threads = 256 consecutive columns
__global__ __launch_bounds__(256) void colpart_kernel(
    const float* __restrict__ C, const float* __restrict__ u,
    float* __restrict__ pmax, float* __restrict__ psum) {
  int tid = threadIdx.x;
  int bid = blockIdx.x;
  int s = bid & (SPLIT_ - 1);
  int rest = bid >> 4;
  int mt = rest & 7;  // M_/256 = 8
  int b = rest >> 3;
  int m = (mt << 8) + tid;
  const float* Cp = C + ((size_t)b * N_ + (size_t)s * CHUNK_) * M_ + m;
  const float* up = u + b * N_ + s * CHUNK_;
  float mr = -INFINITY, sr = 0.f;
#pragma unroll 4
  for (int i = 0; i < CHUNK_; i++) {
    float x = (up[i] - Cp[(size_t)i * M_]) * SCALE_;
    float mn = fmaxf(mr, x);
    sr = sr * exp2f(mr - mn) + exp2f(x - mn);
    mr = mn;
  }
  int idx = (s * B_ + b) * M_ + m;
  pmax[idx] = mr;
  psum[idx] = sr;
}

// combine SPLIT_ partials per column -> v[b,m]
__global__ __launch_bounds__(256) void combine_kernel(
    const float* __restrict__ pmax, const float* __restrict__ psum,
    const float* __restrict__ q, float* __restrict__ v) {
  int gid = blockIdx.x * 256 + threadIdx.x;  // b*M_ + m
  int b = gid >> 11;
  int m = gid & (M_ - 1);
  float mr = -INFINITY, sr = 0.f;
#pragma unroll
  for (int s = 0; s < SPLIT_; s++) {
    int idx = (s * B_ + b) * M_ + m;
    float pm = pmax[idx], ps = psum[idx];
    float mn = fmaxf(mr, pm);
    sr = sr * exp2f(mr - mn) + ps * exp2f(pm - mn);
    mr = mn;
  }
  float lse = LN2_ * (mr + log2f(sr));
  v[gid] = 0.1f * (logf(q[gid] + 1e-8f) - lse);
}

// pi = exp((u + v - C)/eps); one block per row
__global__ __launch_bounds__(256) void pi_kernel(
    const float* __restrict__ C, const float* __restrict__ u,
    const float* __restrict__ v, float* __restrict__ out) {
  int bid = blockIdx.x;
  int tid = threadIdx.x;
  int b = bid >> 11;
  float uu = u[bid];
  const float4* Cr = (const float4*)(C + (size_t)bid * M_);
  const float4* vr = (const float4*)(v + (size_t)b * M_);
  float4* Or = (float4*)(out + (size_t)bid * M_);
#pragma unroll
  for (int k = 0; k < 2; k++) {
    int i = tid + (k << 8);
    float4 c = Cr[i], vv = vr[i];
    float4 r;
    r.x = exp2f((uu + vv.x - c.x) * SCALE_);
    r.y = exp2f((uu + vv.y - c.y) * SCALE_);
    r.z = exp2f((uu + vv.z - c.z) * SCALE_);
    r.w = exp2f((uu + vv.w - c.w) * SCALE_);
    Or[i] = r;
  }
}

extern "C" void kernel_launch(void* const* d_in, const int* in_sizes, int n_in,
                              void* d_out, int out_size, void* d_ws, size_t ws_size,
                              hipStream_t stream) {
  const float* p = (const float*)d_in[0];
  const float* q = (const float*)d_in[1];
  const float* C = (const float*)d_in[2];
  float* out = (float*)d_out;

  float* u = (float*)d_ws;   // B_*N_
  float* v = u + B_ * N_;    // B_*M_
  size_t need_full = (size_t)(B_ * N_ + B_ * M_ + 2 * SPLIT_ * B_ * M_) * sizeof(float);
  float* pmax;
  if (ws_size >= need_full) {
    pmax = v + B_ * M_;
  } else {
    // fall back to using d_out as scratch for partials; pi_kernel rewrites
    // all of d_out at the end, so this is safe and deterministic.
    pmax = out;
  }
  float* psum = pmax + SPLIT_ * B_ * M_;

  hipMemsetAsync(u, 0, (size_t)(B_ * N_ + B_ * M_) * sizeof(float), stream);

  for (int it = 0; it < ITERS_; ++it) {
    row_kernel<<<B_ * N_, 256, 0, stream>>>(C, p, v, u);
    colpart_kernel<<<B_ * (M_ / 256) * SPLIT_, 256, 0, stream>>>(C, u, pmax, psum);
    combine_kernel<<<B_ * M_ / 256, 256, 0, stream>>>(pmax, psum, q, v);
  }
  pi_kernel<<<B_ * N_, 256, 0, stream>>>(C, u, v, out);
}

// Round 2
// 8319.045 us; speedup vs baseline: 1.0190x; 1.0190x over previous
//
#include <hip/hip_runtime.h>
#include <math.h>

#define B_ 16
#define N_ 2048
#define M_ 2048
#define ITERS_ 100
#define SPLIT_ 16
#define CHUNK_ (N_ / SPLIT_)

// L3-residency partition: rows n < RES_N_ are read with normal (caching)
// loads and should stay resident in the 256 MiB Infinity Cache (192 MiB);
// rows n >= RES_N_ are read with non-temporal loads (evict-first).
#define RES_N_ 1536
#define RES_S_ (RES_N_ / CHUNK_)  // chunks fully below RES_N_

// (1/eps) * log2(e), eps = 0.1
#define SCALE_ 14.426950408889634f
#define LN2_ 0.69314718055994531f

typedef float f4 __attribute__((ext_vector_type(4)));

static __device__ __forceinline__ float wave_red_max(float x) {
#pragma unroll
  for (int o = 32; o; o >>= 1) x = fmaxf(x, __shfl_xor(x, o, 64));
  return x;
}
static __device__ __forceinline__ float wave_red_sum(float x) {
#pragma unroll
  for (int o = 32; o; o >>= 1) x += __shfl_xor(x, o, 64);
  return x;
}

// u[b,n] = eps*(log(p+1e-8) - LSE_m((v[b,m]-C[b,n,m])/eps))
// one block per (b,n) row; 256 threads x 8 elements (2x float4)
__global__ __launch_bounds__(256) void row_kernel(
    const float* __restrict__ C, const float* __restrict__ p,
    const float* __restrict__ v, float* __restrict__ u) {
  int bid = blockIdx.x;  // b*N_ + n
  int tid = threadIdx.x;
  int b = bid >> 11;  // N_ = 2048
  int n = bid & (N_ - 1);
  const f4* Cr = (const f4*)(C + (size_t)bid * M_);
  const f4* vr = (const f4*)(v + (size_t)b * M_);
  f4 c0, c1;
  if (n < RES_N_) {
    c0 = Cr[tid];
    c1 = Cr[tid + 256];
  } else {
    c0 = __builtin_nontemporal_load(&Cr[tid]);
    c1 = __builtin_nontemporal_load(&Cr[tid + 256]);
  }
  f4 v0 = vr[tid], v1 = vr[tid + 256];
  float t[8];
  t[0] = (v0.x - c0.x) * SCALE_;
  t[1] = (v0.y - c0.y) * SCALE_;
  t[2] = (v0.z - c0.z) * SCALE_;
  t[3] = (v0.w - c0.w) * SCALE_;
  t[4] = (v1.x - c1.x) * SCALE_;
  t[5] = (v1.y - c1.y) * SCALE_;
  t[6] = (v1.z - c1.z) * SCALE_;
  t[7] = (v1.w - c1.w) * SCALE_;
  float tm = t[0];
#pragma unroll
  for (int j = 1; j < 8; j++) tm = fmaxf(tm, t[j]);

  __shared__ float sred[8];
  int lane = tid & 63, wid = tid >> 6;
  float wm = wave_red_max(tm);
  if (!lane) sred[wid] = wm;
  __syncthreads();
  float bm = fmaxf(fmaxf(sred[0], sred[1]), fmaxf(sred[2], sred[3]));

  float s = 0.f;
#pragma unroll
  for (int j = 0; j < 8; j++) s += exp2f(t[j] - bm);
  float wsum = wave_red_sum(s);
  if (!lane) sred[4 + wid] = wsum;
  __syncthreads();
  if (!tid) {
    float bs = sred[4] + sred[5] + sred[6] + sred[7];
    float lse = LN2_ * (bm + log2f(bs));
    u[bid] = 0.1f * (logf(p[bid] + 1e-8f) - lse);
  }
}

// partial column LSE over an n-chunk: online (max,sum) per column
// grid = B_ * (M_/256) * SPLIT_; 256 threads = 256 consecutive columns
__global__ __launch_bounds__(256) void colpart_kernel(
    const float* __restrict__ C, const float* __restrict__ u,
    float* __restrict__ pmax, float* __restrict__ psum) {
  int tid = threadIdx.x;
  int bid = blockIdx.x;
  int s = bid & (SPLIT_ - 1);
  int rest = bid >> 4;
  int mt = rest & 7;  // M_/256 = 8
  int b = rest >> 3;
  int m = (mt << 8) + tid;
  const float* Cp = C + ((size_t)b * N_ + (size_t)s * CHUNK_) * M_ + m;
  const float* up = u + b * N_ + s * CHUNK_;
  float mr = -INFINITY, sr = 0.f;
  if (s < RES_S_) {
#pragma unroll 4
    for (int i = 0; i < CHUNK_; i++) {
      float x = (up[i] - Cp[(size_t)i * M_]) * SCALE_;
      float mn = fmaxf(mr, x);
      sr = sr * exp2f(mr - mn) + exp2f(x - mn);
      mr = mn;
    }
  } else {
#pragma unroll 4
    for (int i = 0; i < CHUNK_; i++) {
      float c = __builtin_nontemporal_load(&Cp[(size_t)i * M_]);
      float x = (up[i] - c) * SCALE_;
      float mn = fmaxf(mr, x);
      sr = sr * exp2f(mr - mn) + exp2f(x - mn);
      mr = mn;
    }
  }
  int idx = (s * B_ + b) * M_ + m;
  pmax[idx] = mr;
  psum[idx] = sr;
}

// combine SPLIT_ partials per column -> v[b,m]
__global__ __launch_bounds__(256) void combine_kernel(
    const float* __restrict__ pmax, const float* __restrict__ psum,
    const float* __restrict__ q, float* __restrict__ v) {
  int gid = blockIdx.x * 256 + threadIdx.x;  // b*M_ + m
  int b = gid >> 11;
  int m = gid & (M_ - 1);
  float mr = -INFINITY, sr = 0.f;
#pragma unroll
  for (int s = 0; s < SPLIT_; s++) {
    int idx = (s * B_ + b) * M_ + m;
    float pm = pmax[idx], ps = psum[idx];
    float mn = fmaxf(mr, pm);
    sr = sr * exp2f(mr - mn) + ps * exp2f(pm - mn);
    mr = mn;
  }
  float lse = LN2_ * (mr + log2f(sr));
  v[gid] = 0.1f * (logf(q[gid] + 1e-8f) - lse);
}

// pi = exp((u + v - C)/eps); one block per row; fully non-temporal
__global__ __launch_bounds__(256) void pi_kernel(
    const float* __restrict__ C, const float* __restrict__ u,
    const float* __restrict__ v, float* __restrict__ out) {
  int bid = blockIdx.x;
  int tid = threadIdx.x;
  int b = bid >> 11;
  float uu = u[bid];
  const f4* Cr = (const f4*)(C + (size_t)bid * M_);
  const f4* vr = (const f4*)(v + (size_t)b * M_);
  f4* Or = (f4*)(out + (size_t)bid * M_);
#pragma unroll
  for (int k = 0; k < 2; k++) {
    int i = tid + (k << 8);
    f4 c = __builtin_nontemporal_load(&Cr[i]);
    f4 vv = vr[i];
    f4 r;
    r.x = exp2f((uu + vv.x - c.x) * SCALE_);
    r.y = exp2f((uu + vv.y - c.y) * SCALE_);
    r.z = exp2f((uu + vv.z - c.z) * SCALE_);
    r.w = exp2f((uu + vv.w - c.w) * SCALE_);
    __builtin_nontemporal_store(r, &Or[i]);
  }
}

extern "C" void kernel_launch(void* const* d_in, const int* in_sizes, int n_in,
                              void* d_out, int out_size, void* d_ws, size_t ws_size,
                              hipStream_t stream) {
  const float* p = (const float*)d_in[0];
  const float* q = (const float*)d_in[1];
  const float* C = (const float*)d_in[2];
  float* out = (float*)d_out;

  float* u = (float*)d_ws;   // B_*N_
  float* v = u + B_ * N_;    // B_*M_
  size_t need_full = (size_t)(B_ * N_ + B_ * M_ + 2 * SPLIT_ * B_ * M_) * sizeof(float);
  float* pmax;
  if (ws_size >= need_full) {
    pmax = v + B_ * M_;
  } else {
    // fall back to using d_out as scratch for partials; pi_kernel rewrites
    // all of d_out at the end, so this is safe and deterministic.
    pmax = out;
  }
  float* psum = pmax + SPLIT_ * B_ * M_;

  hipMemsetAsync(u, 0, (size_t)(B_ * N_ + B_ * M_) * sizeof(float), stream);

  for (int it = 0; it < ITERS_; ++it) {
    row_kernel<<<B_ * N_, 256, 0, stream>>>(C, p, v, u);
    colpart_kernel<<<B_ * (M_ / 256) * SPLIT_, 256, 0, stream>>>(C, u, pmax, psum);
    combine_kernel<<<B_ * M_ / 256, 256, 0, stream>>>(pmax, psum, q, v);
  }
  pi_kernel<<<B_ * N_, 256, 0, stream>>>(C, u, v, out);
}

// Round 3
// 5142.693 us; speedup vs baseline: 1.6484x; 1.6176x over previous
//
#include <hip/hip_runtime.h>
#include <math.h>

#define B_ 16
#define N_ 2048
#define M_ 2048
#define ITERS_ 100
#define RCH_ 64               // rows per chunk
#define NCH_ (N_ / RCH_)      // 32 chunks
// (1/eps)*log2(e), eps = 0.1
#define SCALE_ 14.426950408889634f

typedef float f4 __attribute__((ext_vector_type(4)));

// Fused Sinkhorn iteration, exp-domain factorization.
//   g[n] = e^{u[n]/eps} = (p+1e-8)/rowsum,  F[m] = e^{v[m]/eps} = (q+1e-8)/colsum
// Block (b, s) owns rows [s*64, s*64+64). 256 threads = 4 waves; wave w owns
// 16 rows. Lane l owns columns {k*256 + 4l + j : k=0..7, j=0..3} (coalesced
// float4 loads). Per row: e[k] = 2^(lF[k] - S*C) (lF = log2 F), rowsum ->
// wave shuffle reduce -> g = p'/rs -> col partial sr[k] += e[k]*g (same data,
// no re-read). End: cross-wave LDS sum of sr, store psum_out = sr_tot/F
// (true partial col sums of e^{(u-C)/eps}).
template <int FIRST>
__global__ __launch_bounds__(256, 2) void sink_iter(
    const float* __restrict__ C, const float* __restrict__ p,
    const float* __restrict__ q, const float* __restrict__ psum_in,
    float* __restrict__ psum_out, float* __restrict__ g_out) {
  __shared__ float lds[4][M_];  // 32 KB
  const int tid = threadIdx.x;
  const int lane = tid & 63, w = tid >> 6;
  const int bid = blockIdx.x;
  const int b = bid >> 5, s = bid & (NCH_ - 1);

  f4 lF[8];   // log2(F) for owned columns
  f4 F2[2];   // F for the two k-slots this wave writes at the end
  if (FIRST) {
#pragma unroll
    for (int k = 0; k < 8; k++) lF[k] = f4{0.f, 0.f, 0.f, 0.f};
    F2[0] = f4{1.f, 1.f, 1.f, 1.f};
    F2[1] = f4{1.f, 1.f, 1.f, 1.f};
  } else {
    // partial column sums: wave w sums 8 chunks
    f4 S[8];
#pragma unroll
    for (int k = 0; k < 8; k++) S[k] = f4{0.f, 0.f, 0.f, 0.f};
    for (int s2 = w * 8; s2 < w * 8 + 8; s2++) {
      const f4* P = (const f4*)(psum_in + (size_t)(s2 * B_ + b) * M_);
#pragma unroll
      for (int k = 0; k < 8; k++) S[k] += P[k * 64 + lane];
    }
#pragma unroll
    for (int k = 0; k < 8; k++) *(f4*)&lds[w][k * 256 + lane * 4] = S[k];
    __syncthreads();
    const f4* Q = (const f4*)(q + (size_t)b * M_);
#pragma unroll
    for (int k = 0; k < 8; k++) {
      int ci = k * 256 + lane * 4;
      f4 t = *(const f4*)&lds[0][ci] + *(const f4*)&lds[1][ci] +
             *(const f4*)&lds[2][ci] + *(const f4*)&lds[3][ci];
      f4 qq = Q[k * 64 + lane];
      f4 F;
      F.x = (qq.x + 1e-8f) / t.x;
      F.y = (qq.y + 1e-8f) / t.y;
      F.z = (qq.z + 1e-8f) / t.z;
      F.w = (qq.w + 1e-8f) / t.w;
      lF[k].x = log2f(F.x);
      lF[k].y = log2f(F.y);
      lF[k].z = log2f(F.z);
      lF[k].w = log2f(F.w);
      if (k == w * 2) F2[0] = F;
      if (k == w * 2 + 1) F2[1] = F;
    }
    __syncthreads();  // lds reads done before end-phase writes
  }

  f4 sr[8];
#pragma unroll
  for (int k = 0; k < 8; k++) sr[k] = f4{0.f, 0.f, 0.f, 0.f};

  const int row0 = s * RCH_ + w * 16;
  const float* prow = p + (size_t)b * N_ + row0;
  const float* Crow = C + ((size_t)b * N_ + row0) * M_;

#pragma unroll 2
  for (int i = 0; i < 16; i++) {
    const f4* Cr = (const f4*)(Crow + (size_t)i * M_);
    f4 e[8];
    float rs = 0.f;
#pragma unroll
    for (int k = 0; k < 8; k++) {
      f4 c = Cr[k * 64 + lane];
      f4 t;
      t.x = exp2f(fmaf(-SCALE_, c.x, lF[k].x));
      t.y = exp2f(fmaf(-SCALE_, c.y, lF[k].y));
      t.z = exp2f(fmaf(-SCALE_, c.z, lF[k].z));
      t.w = exp2f(fmaf(-SCALE_, c.w, lF[k].w));
      e[k] = t;
      rs += (t.x + t.y) + (t.z + t.w);
    }
#pragma unroll
    for (int o = 32; o; o >>= 1) rs += __shfl_xor(rs, o, 64);
    float g = (prow[i] + 1e-8f) / rs;
    if (lane == 0) g_out[(size_t)b * N_ + row0 + i] = g;
#pragma unroll
    for (int k = 0; k < 8; k++) sr[k] += e[k] * g;
  }

  // cross-wave column reduction; psum_out = total / F (remove the F factor)
#pragma unroll
  for (int k = 0; k < 8; k++) *(f4*)&lds[w][k * 256 + lane * 4] = sr[k];
  __syncthreads();
#pragma unroll
  for (int k2 = 0; k2 < 2; k2++) {
    int k = w * 2 + k2;
    int ci = k * 256 + lane * 4;
    f4 tot = *(const f4*)&lds[0][ci] + *(const f4*)&lds[1][ci] +
             *(const f4*)&lds[2][ci] + *(const f4*)&lds[3][ci];
    f4 r = tot / F2[k2];
    *(f4*)&psum_out[(size_t)(s * B_ + b) * M_ + ci] = r;
  }
}

// F[b,m] = (q+1e-8)/S_col from the last iteration's partials
__global__ __launch_bounds__(256) void fin_F(
    const float* __restrict__ psum, const float* __restrict__ q,
    float* __restrict__ F) {
  int gid = blockIdx.x * 256 + threadIdx.x;  // b*M_ + m
  int b = gid >> 11;
  int m = gid & (M_ - 1);
  float Ssum = 0.f;
#pragma unroll
  for (int s = 0; s < NCH_; s++)
    Ssum += psum[(size_t)(s * B_ + b) * M_ + m];
  F[gid] = (q[gid] + 1e-8f) / Ssum;
}

// pi = g[n] * F[m] * 2^(-C*S); one block per (b,n) row
__global__ __launch_bounds__(256) void pi_kernel(
    const float* __restrict__ C, const float* __restrict__ g_arr,
    const float* __restrict__ Fv, float* __restrict__ out) {
  int bid = blockIdx.x;
  int tid = threadIdx.x;
  int b = bid >> 11;
  float gg = g_arr[bid];
  const f4* Cr = (const f4*)(C + (size_t)bid * M_);
  const f4* Fr = (const f4*)(Fv + (size_t)b * M_);
  f4* Or = (f4*)(out + (size_t)bid * M_);
#pragma unroll
  for (int k = 0; k < 2; k++) {
    int i = tid + (k << 8);
    f4 c = Cr[i], f = Fr[i];
    f4 r;
    r.x = gg * f.x * exp2f(-SCALE_ * c.x);
    r.y = gg * f.y * exp2f(-SCALE_ * c.y);
    r.z = gg * f.z * exp2f(-SCALE_ * c.z);
    r.w = gg * f.w * exp2f(-SCALE_ * c.w);
    Or[i] = r;
  }
}

extern "C" void kernel_launch(void* const* d_in, const int* in_sizes, int n_in,
                              void* d_out, int out_size, void* d_ws, size_t ws_size,
                              hipStream_t stream) {
  const float* p = (const float*)d_in[0];
  const float* q = (const float*)d_in[1];
  const float* C = (const float*)d_in[2];
  float* out = (float*)d_out;

  const size_t psz = (size_t)NCH_ * B_ * M_;           // 1,048,576 floats
  const size_t gsz = (size_t)B_ * N_;                  // 32768
  const size_t fsz = (size_t)B_ * M_;                  // 32768
  const size_t need_all = (2 * psz + gsz + fsz) * sizeof(float);  // ~8.65 MB

  float *pA, *pB, *g_arr, *Fv;
  if (ws_size >= need_all) {
    pA = (float*)d_ws;
    pB = pA + psz;
    g_arr = pB + psz;
    Fv = g_arr + gsz;
  } else {
    // g,F in ws (256 KB); psum ping-pong in the tail of d_out. The partials
    // are consumed by fin_F before pi_kernel rewrites all of d_out, and
    // pi_kernel reads only C, g, F -> no conflict.
    g_arr = (float*)d_ws;
    Fv = g_arr + gsz;
    pA = out + ((size_t)out_size - 2 * psz);
    pB = pA + psz;
  }

  for (int t = 0; t < ITERS_; ++t) {
    const float* pin = (t & 1) ? pA : pB;  // unused when t==0
    float* pout = (t & 1) ? pB : pA;
    if (t == 0)
      sink_iter<1><<<B_ * NCH_, 256, 0, stream>>>(C, p, q, pA, pout, g_arr);
    else
      sink_iter<0><<<B_ * NCH_, 256, 0, stream>>>(C, p, q, pin, pout, g_arr);
  }
  // t=99 (odd) wrote pB
  fin_F<<<B_ * M_ / 256, 256, 0, stream>>>(pB, q, Fv);
  pi_kernel<<<B_ * N_, 256, 0, stream>>>(C, g_arr, Fv, out);
}

// Round 4
// 3640.199 us; speedup vs baseline: 2.3287x; 1.4128x over previous
//
#include <hip/hip_runtime.h>
#include <math.h>

#define B_ 16
#define N_ 2048
#define M_ 2048
#define ITERS_ 100
#define RCH_ 64               // rows per chunk
#define NCH_ (N_ / RCH_)      // 32 chunks
// (1/eps)*log2(e), eps = 0.1
#define SCALE_ 14.426950408889634f
// scale for u16 fixed-point C: Chat = c16/65535
#define KQ_ (SCALE_ / 65535.0f)

typedef float f4 __attribute__((ext_vector_type(4)));
typedef unsigned short u16x4 __attribute__((ext_vector_type(4)));
typedef unsigned short u16x8 __attribute__((ext_vector_type(8)));

// C (fp32, [0,1)) -> u16 fixed point. One thread = 8 elements.
__global__ __launch_bounds__(256) void conv_kernel(
    const float* __restrict__ C, unsigned short* __restrict__ c16) {
  size_t t = (size_t)blockIdx.x * 256 + threadIdx.x;
  const f4* Cr = (const f4*)C;
  f4 a = __builtin_nontemporal_load(&Cr[2 * t]);
  f4 b = __builtin_nontemporal_load(&Cr[2 * t + 1]);
  u16x8 o;
  o[0] = (unsigned short)rintf(a.x * 65535.f);
  o[1] = (unsigned short)rintf(a.y * 65535.f);
  o[2] = (unsigned short)rintf(a.z * 65535.f);
  o[3] = (unsigned short)rintf(a.w * 65535.f);
  o[4] = (unsigned short)rintf(b.x * 65535.f);
  o[5] = (unsigned short)rintf(b.y * 65535.f);
  o[6] = (unsigned short)rintf(b.z * 65535.f);
  o[7] = (unsigned short)rintf(b.w * 65535.f);
  *(u16x8*)&c16[t * 8] = o;  // plain store: want L3 allocation (reused 99x)
}

__global__ __launch_bounds__(256) void init_kernel(float* __restrict__ lF) {
  lF[blockIdx.x * 256 + threadIdx.x] = 0.f;
}

// One fused Sinkhorn iteration (exp-domain, factorized):
//   g[n] = p'/rowsum_n,  rowsum_n = sum_m 2^(lF[m] - S*C[n,m])
//   psum[s][b][m] = sum_{n in chunk s} g[n] * 2^(lF[m] - S*C[n,m])
// Block (b,s) owns 64 rows; 4 waves x 16 rows; lane l owns cols
// {k*256+4l+j}. One C read serves both row LSE and column partials.
template <int U16>
__global__ __launch_bounds__(256, 2) void sink_iter(
    const void* __restrict__ Cv, const float* __restrict__ p,
    const float* __restrict__ lF_arr, float* __restrict__ psum,
    float* __restrict__ g_out) {
  __shared__ float lds[4][M_];  // 32 KB
  const int tid = threadIdx.x;
  const int lane = tid & 63, w = tid >> 6;
  const int bid = blockIdx.x;
  const int b = bid >> 5, s = bid & (NCH_ - 1);

  f4 lF[8];
  const f4* lFr = (const f4*)(lF_arr + (size_t)b * M_);
#pragma unroll
  for (int k = 0; k < 8; k++) lF[k] = lFr[k * 64 + lane];

  f4 sr[8];
#pragma unroll
  for (int k = 0; k < 8; k++) sr[k] = f4{0.f, 0.f, 0.f, 0.f};

  const int row0 = s * RCH_ + w * 16;
  const float* prow = p + (size_t)b * N_ + row0;

#pragma unroll 2
  for (int i = 0; i < 16; i++) {
    const size_t roff = ((size_t)b * N_ + row0 + i) * (size_t)M_;
    f4 e[8];
    float rs = 0.f;
#pragma unroll
    for (int k = 0; k < 8; k++) {
      f4 x;
      if (U16) {
        const u16x4* Cr = (const u16x4*)((const unsigned short*)Cv + roff);
        u16x4 c = Cr[k * 64 + lane];
        x.x = fmaf(-KQ_, (float)c.x, lF[k].x);
        x.y = fmaf(-KQ_, (float)c.y, lF[k].y);
        x.z = fmaf(-KQ_, (float)c.z, lF[k].z);
        x.w = fmaf(-KQ_, (float)c.w, lF[k].w);
      } else {
        const f4* Cr = (const f4*)((const float*)Cv + roff);
        f4 c = Cr[k * 64 + lane];
        x.x = fmaf(-SCALE_, c.x, lF[k].x);
        x.y = fmaf(-SCALE_, c.y, lF[k].y);
        x.z = fmaf(-SCALE_, c.z, lF[k].z);
        x.w = fmaf(-SCALE_, c.w, lF[k].w);
      }
      f4 t;
      t.x = exp2f(x.x);
      t.y = exp2f(x.y);
      t.z = exp2f(x.z);
      t.w = exp2f(x.w);
      e[k] = t;
      rs += (t.x + t.y) + (t.z + t.w);
    }
#pragma unroll
    for (int o = 32; o; o >>= 1) rs += __shfl_xor(rs, o, 64);
    float g = (prow[i] + 1e-8f) / rs;
    if (lane == 0) g_out[(size_t)b * N_ + row0 + i] = g;
#pragma unroll
    for (int k = 0; k < 8; k++) sr[k] += e[k] * g;
  }

  // cross-wave column reduction -> psum (raw, includes F factor)
#pragma unroll
  for (int k = 0; k < 8; k++) *(f4*)&lds[w][k * 256 + lane * 4] = sr[k];
  __syncthreads();
#pragma unroll
  for (int k2 = 0; k2 < 2; k2++) {
    int k = w * 2 + k2;
    int ci = k * 256 + lane * 4;
    f4 tot = *(const f4*)&lds[0][ci] + *(const f4*)&lds[1][ci] +
             *(const f4*)&lds[2][ci] + *(const f4*)&lds[3][ci];
    *(f4*)&psum[(size_t)(s * B_ + b) * M_ + ci] = tot;
  }
}

// lF update: Sum_s psum = F_old * colsum_raw; F_new = q'/colsum_raw
//   => lF_new = lF_old + log2(q' / Sum_s psum)
__global__ __launch_bounds__(256) void lfk_kernel(
    const float* __restrict__ psum, const float* __restrict__ q,
    float* __restrict__ lF) {
  int gid = blockIdx.x * 256 + threadIdx.x;  // b*M_ + m
  int b = gid >> 11;
  int m = gid & (M_ - 1);
  float S = 0.f;
#pragma unroll
  for (int s = 0; s < NCH_; s++)
    S += psum[(size_t)(s * B_ + b) * M_ + m];
  lF[gid] += log2f((q[gid] + 1e-8f) / S);
}

// pi = g[n] * 2^(lF[m] - S*C);  fp32 C for exactness
__global__ __launch_bounds__(256) void pi_kernel(
    const float* __restrict__ C, const float* __restrict__ g_arr,
    const float* __restrict__ lF_arr, float* __restrict__ out) {
  int bid = blockIdx.x;
  int tid = threadIdx.x;
  int b = bid >> 11;
  float gg = g_arr[bid];
  const f4* Cr = (const f4*)(C + (size_t)bid * M_);
  const f4* Lr = (const f4*)(lF_arr + (size_t)b * M_);
  f4* Or = (f4*)(out + (size_t)bid * M_);
#pragma unroll
  for (int k = 0; k < 2; k++) {
    int i = tid + (k << 8);
    f4 c = __builtin_nontemporal_load(&Cr[i]);
    f4 L = Lr[i];
    f4 r;
    r.x = gg * exp2f(fmaf(-SCALE_, c.x, L.x));
    r.y = gg * exp2f(fmaf(-SCALE_, c.y, L.y));
    r.z = gg * exp2f(fmaf(-SCALE_, c.z, L.z));
    r.w = gg * exp2f(fmaf(-SCALE_, c.w, L.w));
    __builtin_nontemporal_store(r, &Or[i]);
  }
}

extern "C" void kernel_launch(void* const* d_in, const int* in_sizes, int n_in,
                              void* d_out, int out_size, void* d_ws, size_t ws_size,
                              hipStream_t stream) {
  const float* p = (const float*)d_in[0];
  const float* q = (const float*)d_in[1];
  const float* C = (const float*)d_in[2];
  float* out = (float*)d_out;

  const size_t c16_elems = (size_t)B_ * N_ * M_;        // 67.1M u16 = 134 MB
  const size_t psz = (size_t)NCH_ * B_ * M_;            // 1,048,576 floats
  const size_t gsz = (size_t)B_ * N_;                   // 32768
  const size_t fsz = (size_t)B_ * M_;                   // 32768
  const size_t need_all = c16_elems * 2 + (psz + gsz + fsz) * sizeof(float);

  unsigned short* c16;
  float *psum, *g_arr, *lF;
  if (ws_size >= need_all) {
    c16 = (unsigned short*)d_ws;
    psum = (float*)(c16 + c16_elems);
    g_arr = psum + psz;
    lF = g_arr + gsz;
  } else {
    // g, lF in ws (256 KB — the minimum already exercised in prior rounds);
    // c16 in the front of d_out, psum in its tail. All scratch uses of d_out
    // complete before pi_kernel rewrites d_out, and pi reads only C/g/lF.
    g_arr = (float*)d_ws;
    lF = g_arr + gsz;
    c16 = (unsigned short*)d_out;                       // 134.2 MB
    psum = out + ((size_t)out_size - psz);              // last 4 MB
  }

  conv_kernel<<<(int)(c16_elems / (256 * 8)), 256, 0, stream>>>(C, c16);
  init_kernel<<<(B_ * M_) / 256, 256, 0, stream>>>(lF);

  for (int t = 0; t < ITERS_; ++t) {
    if (t < ITERS_ - 1)
      sink_iter<1><<<B_ * NCH_, 256, 0, stream>>>(c16, p, lF, psum, g_arr);
    else  // final iteration with exact fp32 C
      sink_iter<0><<<B_ * NCH_, 256, 0, stream>>>(C, p, lF, psum, g_arr);
    lfk_kernel<<<(B_ * M_) / 256, 256, 0, stream>>>(psum, q, lF);
  }
  pi_kernel<<<B_ * N_, 256, 0, stream>>>(C, g_arr, lF, out);
}